// Round 1
// baseline (209.997 us; speedup 1.0000x reference)
//
#include <hip/hip_runtime.h>
#include <math.h>

// B=16, C=512, HW=1024.  Chain (per batch):
//   X  (C x HW)  = n1 @ W_c^T
//   E  (HW x HW) = X^T @ n2
//   A  = row-softmax(E)
//   out(C x HW)  = n2 @ A
//
// Round 8: softmax-transpose fusion + deeper staging prefetch.
//  - gemm2 now writes Et[h][o] = E[o][h] directly via the proven LDS-transpose
//    epilogue (from gemm1). The tr_scale pass is DELETED: At[j][o] is an
//    elementwise scale of Et, fused into gemm3's B-staging as
//    exp(Et - C_o) with C_o = m_o + log(sum_o)  (one FMA + __expf per elem,
//    overlapped with MFMA).
//  - softmax stats become a coalesced column-reduce over Et:
//    stats_partial (256 blocks, online max/sum over 64-row chunks) +
//    stats_combine (tiny).
//  - GEMM core for gemm1/gemm2: 2-deep global->reg prefetch (register sets
//    pa0/pa1 with compile-time slot parity) so the vmcnt wait at ds_write
//    covers ~2 K-steps of latency instead of 1. gemm3 keeps depth-1 (carries
//    scale constants instead).
//
// Workspace (96 MiB, lifetime-aliased):
//   [0,16M):   n2t  f16 (prep -> gemm2)
//   [16,32M):  Xt   f16 (gemm1 -> gemm2)
//   [32,34M):  Wf   f16 (prep -> gemm1; overlaid by Et)
//   [32,64M):  Et   f16 (gemm2 -> stats -> gemm3)
//   [64,80M):  n1f  f16 (prep -> gemm1); Pm/Ps/Sc overlay afterwards
//   [80,96M):  n2f  f16 (prep -> gemm3)

typedef _Float16 f16;
typedef _Float16 f16x8 __attribute__((ext_vector_type(8)));
typedef _Float16 f16x4 __attribute__((ext_vector_type(4)));
typedef float f32x4 __attribute__((ext_vector_type(4)));

// Barrier with LDS-drain only (no vmcnt drain): prefetch survives it.
#define WG_BARRIER() asm volatile("s_waitcnt lgkmcnt(0)\ns_barrier" ::: "memory")

// ---------------------------------------------------------------------------
// Fused pre-pass (unchanged). blockIdx.x:
//   [0,4096):    n1 -> n1f     [4096,4608): Wc -> Wf
//   [4608,6656): n2 -> n2f (natural) + n2t (transposed)
__global__ __launch_bounds__(256) void prep(const float* __restrict__ n1,
                                            const float* __restrict__ Wc,
                                            const float* __restrict__ n2,
                                            f16* __restrict__ n1f, f16* __restrict__ Wf,
                                            f16* __restrict__ n2f, f16* __restrict__ n2t) {
    const int bid = blockIdx.x, tid = threadIdx.x;
    if (bid < 4608) {
        const float* s = (bid < 4096) ? n1 : Wc;
        f16* d = (bid < 4096) ? n1f : Wf;
        const size_t i = ((size_t)(bid < 4096 ? bid : bid - 4096) * 256 + tid) * 8;
        f32x4 a = *(const f32x4*)(s + i);
        f32x4 b = *(const f32x4*)(s + i + 4);
        f16x8 o;
        o[0] = (f16)a[0]; o[1] = (f16)a[1]; o[2] = (f16)a[2]; o[3] = (f16)a[3];
        o[4] = (f16)b[0]; o[5] = (f16)b[1]; o[6] = (f16)b[2]; o[7] = (f16)b[3];
        *(f16x8*)(d + i) = o;
        return;
    }
    const int id = bid - 4608;
    const int b = id >> 7;
    const int ry = (id & 127) >> 4;
    const int cx = id & 15;
    const float* S = n2 + (size_t)b * 512 * 1024;
    f16* Dn = n2f + (size_t)b * 512 * 1024;
    f16* Dt = n2t + (size_t)b * 1024 * 512;
    __shared__ f16 Ts[64 * 72];
    const int r0 = ry * 64, c0 = cx * 64;
    const int rr = tid >> 3, cc8 = (tid & 7) * 8;
#pragma unroll
    for (int h = 0; h < 2; ++h) {
        const int row = r0 + rr + 32 * h;
        const float* s = S + (size_t)row * 1024 + c0 + cc8;
        f32x4 a = *(const f32x4*)s, bq = *(const f32x4*)(s + 4);
        f16x8 o;
        o[0] = (f16)a[0]; o[1] = (f16)a[1]; o[2] = (f16)a[2]; o[3] = (f16)a[3];
        o[4] = (f16)bq[0]; o[5] = (f16)bq[1]; o[6] = (f16)bq[2]; o[7] = (f16)bq[3];
        *(f16x8*)&Ts[(rr + 32 * h) * 72 + cc8] = o;
        *(f16x8*)(Dn + (size_t)row * 1024 + c0 + cc8) = o;
    }
    __syncthreads();
    const int j = tid >> 2, k16 = (tid & 3) * 16;
    f16* d = Dt + (size_t)(c0 + j) * 512 + r0 + k16;
    f16x8 o0, o1;
#pragma unroll
    for (int i = 0; i < 8; ++i) {
        o0[i] = Ts[(k16 + i) * 72 + j];
        o1[i] = Ts[(k16 + 8 + i) * 72 + j];
    }
    *(f16x8*)d = o0;
    *(f16x8*)(d + 8) = o1;
}

// ---------------------------------------------------------------------------
// Column-softmax stats over Et[h][o] (softmax rows of E = columns of Et).
// stats_partial: 16 batches x 16 row-chunks (64 rows). Thread t owns 4
// consecutive o; online max/sum streaming the chunk (coalesced f16x4 loads).
__global__ __launch_bounds__(256) void stats_partial(const f16* __restrict__ Et,
                                                     float* __restrict__ Pm,
                                                     float* __restrict__ Ps) {
    const int b = blockIdx.x & 15, chunk = blockIdx.x >> 4;
    const int t = threadIdx.x;
    const f16* p = Et + (size_t)b * 1024 * 1024 + (size_t)chunk * 64 * 1024 + t * 4;
    float m[4] = {-3.0e38f, -3.0e38f, -3.0e38f, -3.0e38f};
    float s[4] = {0.f, 0.f, 0.f, 0.f};
#pragma unroll 4
    for (int j = 0; j < 64; ++j) {
        f16x4 v4 = *(const f16x4*)(p + (size_t)j * 1024);
#pragma unroll
        for (int c = 0; c < 4; ++c) {
            float v = (float)v4[c];
            float nm = fmaxf(m[c], v);
            s[c] = s[c] * __expf(m[c] - nm) + __expf(v - nm);
            m[c] = nm;
        }
    }
    f32x4 mo, so;
#pragma unroll
    for (int c = 0; c < 4; ++c) { mo[c] = m[c]; so[c] = s[c]; }
    *(f32x4*)(Pm + (size_t)(b * 16 + chunk) * 1024 + t * 4) = mo;
    *(f32x4*)(Ps + (size_t)(b * 16 + chunk) * 1024 + t * 4) = so;
}

// stats_combine: per (b,o) fold 16 partials -> Sc[b][o] = m + log(sum).
__global__ __launch_bounds__(256) void stats_combine(const float* __restrict__ Pm,
                                                     const float* __restrict__ Ps,
                                                     float* __restrict__ Sc) {
    const int g = blockIdx.x * 256 + threadIdx.x;  // 16 * 1024
    const int b = g >> 10, o = g & 1023;
    const float* pm = Pm + (size_t)b * 16 * 1024 + o;
    const float* ps = Ps + (size_t)b * 16 * 1024 + o;
    float M = -3.0e38f;
#pragma unroll
    for (int c = 0; c < 16; ++c) M = fmaxf(M, pm[c * 1024]);
    float S = 0.f;
#pragma unroll
    for (int c = 0; c < 16; ++c) S += ps[c * 1024] * __expf(pm[c * 1024] - M);
    Sc[g] = M + __logf(S);
}

// ---------------------------------------------------------------------------
// Double-buffered K-loop core, 2-deep global->reg prefetch (gemm1/gemm2).
//   SM layout: A0[8K] A1[8K] B0[8K] B1[8K]  (row-major 128x32 f16 each)
//   per-thread stage slot: 16 B at off = wave*1024 + lane*16
//   Set s_n lives in p{a,b}(n&1); at step kb we ds_write s_{kb+1} and load
//   s_{kb+3} into the slot just consumed. Loads get ~2 K-steps of cover.
#define GEMM_CORE_D2(NS)                                                                \
    f16x8 pa0 = *(const f16x8*)gAp, pb0 = *(const f16x8*)gBp;                           \
    *(f16x8*)wA0 = pa0; *(f16x8*)wB0 = pb0;                                             \
    f16x8 pa1 = *(const f16x8*)(gAp + 64), pb1 = *(const f16x8*)(gBp + 64);             \
    pa0 = *(const f16x8*)(gAp + 128); pb0 = *(const f16x8*)(gBp + 128);                 \
    WG_BARRIER();                                                                       \
    f32x4 acc[4][2] = {};                                                               \
_Pragma("unroll")                                                                       \
    for (int kb = 0; kb < (NS); ++kb) {                                                 \
        const f16* Ac = (const f16*)(SM + (kb & 1) * 8192);                             \
        const f16* Bc = (const f16*)(SM + 16384 + (kb & 1) * 8192);                     \
        f16x8 fa[4], fb[2];                                                             \
_Pragma("unroll")                                                                       \
        for (int u = 0; u < 4; ++u)                                                     \
            fa[u] = *(const f16x8*)&Ac[(wm + u * 16 + col) * 32 + quad * 8];            \
_Pragma("unroll")                                                                       \
        for (int v = 0; v < 2; ++v)                                                     \
            fb[v] = *(const f16x8*)&Bc[(wn + v * 16 + col) * 32 + quad * 8];            \
_Pragma("unroll")                                                                       \
        for (int u = 0; u < 4; ++u)                                                     \
_Pragma("unroll")                                                                       \
            for (int v = 0; v < 2; ++v)                                                 \
                acc[u][v] = __builtin_amdgcn_mfma_f32_16x16x32_f16(fa[u], fb[v],        \
                                                                   acc[u][v], 0, 0, 0);\
        if (kb + 1 < (NS)) {                                                            \
            char* dA = SM + ((kb + 1) & 1) * 8192 + off;                                \
            char* dB = SM + 16384 + ((kb + 1) & 1) * 8192 + off;                        \
            if ((kb & 1) == 0) {                                                        \
                *(f16x8*)dA = pa1; *(f16x8*)dB = pb1;                                   \
                if (kb + 3 < (NS)) {                                                    \
                    pa1 = *(const f16x8*)(gAp + (size_t)(kb + 3) * 64);                 \
                    pb1 = *(const f16x8*)(gBp + (size_t)(kb + 3) * 64);                 \
                }                                                                       \
            } else {                                                                    \
                *(f16x8*)dA = pa0; *(f16x8*)dB = pb0;                                   \
                if (kb + 3 < (NS)) {                                                    \
                    pa0 = *(const f16x8*)(gAp + (size_t)(kb + 3) * 64);                 \
                    pb0 = *(const f16x8*)(gBp + (size_t)(kb + 3) * 64);                 \
                }                                                                       \
            }                                                                           \
            WG_BARRIER();                                                               \
        }                                                                               \
    }

// ---------------------------------------------------------------------------
// GEMM1: Xt[b][o][c] = (n1f[b] @ Wf^T)^T.  M=512, N=1024, K=1024.
__global__ __launch_bounds__(512) void gemm1_nt_xt(const f16* __restrict__ A,
                                                   const f16* __restrict__ Bw,
                                                   f16* __restrict__ Xt) {
    const int M = 512, K = 1024;
    const int id = blockIdx.x;
    const int xcd = id & 7, loc = id >> 3;
    const int b = xcd * 2 + (loc >> 5);
    const int m0 = ((loc >> 3) & 3) * 128;
    const int n0 = (loc & 7) * 128;
    A += (size_t)b * M * K;
    Xt += (size_t)b * 1024 * M;
    __shared__ __attribute__((aligned(16))) char SM[34816];  // 4x8K bufs; Tt epilogue 34.8K
    const int tid = threadIdx.x, lane = tid & 63, wave = tid >> 6;
    const int col = lane & 15, quad = lane >> 4;
    const int wm = (wave & 1) * 64, wn = (wave >> 1) * 32;
    const int off = wave * 1024 + lane * 16;
    const int srow = off >> 6, scolb = off & 63;
    const char* gAp = (const char*)A + (size_t)(m0 + srow) * K * 2 + scolb;
    const char* gBp = (const char*)Bw + (size_t)(n0 + srow) * K * 2 + scolb;
    char* wA0 = SM + off;
    char* wB0 = SM + 16384 + off;

    GEMM_CORE_D2(32)

    // Transposed epilogue via LDS: Tt[n][m] (pad 136), then coalesced Xt rows.
    WG_BARRIER();  // all frag reads of SM done before overwrite
    f16* Tt = (f16*)SM;
#pragma unroll
    for (int u = 0; u < 4; ++u)
#pragma unroll
        for (int v = 0; v < 2; ++v) {
            f16x4 p;
#pragma unroll
            for (int r = 0; r < 4; ++r) p[r] = (f16)acc[u][v][r];
            *(f16x4*)&Tt[(wn + v * 16 + col) * 136 + wm + u * 16 + quad * 4] = p;
        }
    WG_BARRIER();
    const int j = tid >> 2, seg = (tid & 3) * 32;
    f16* dst = Xt + (size_t)(n0 + j) * M + m0 + seg;
#pragma unroll
    for (int c8 = 0; c8 < 32; c8 += 8)
        *(f16x8*)(dst + c8) = *(const f16x8*)&Tt[j * 136 + seg + c8];
}

// ---------------------------------------------------------------------------
// GEMM2: Et[b][h][o] (f16) = (Xt[b] @ n2t[b]^T)^T.  M=N=1024, K=512.
// Transposed output via the same LDS epilogue as gemm1 -> tr_scale pass dies.
__global__ __launch_bounds__(512) void gemm2_nt_et(const f16* __restrict__ A,
                                                   const f16* __restrict__ B,
                                                   f16* __restrict__ Et) {
    const int K = 512;
    const int id = blockIdx.x;
    const int xcd = id & 7, loc = id >> 3;
    const int b = xcd * 2 + (loc >> 6);
    const int m0 = ((loc >> 3) & 7) * 128;
    const int n0 = (loc & 7) * 128;
    A += (size_t)b * 1024 * K;
    B += (size_t)b * 1024 * K;
    Et += (size_t)b * 1024 * 1024;
    __shared__ __attribute__((aligned(16))) char SM[34816];
    const int tid = threadIdx.x, lane = tid & 63, wave = tid >> 6;
    const int col = lane & 15, quad = lane >> 4;
    const int wm = (wave & 1) * 64, wn = (wave >> 1) * 32;
    const int off = wave * 1024 + lane * 16;
    const int srow = off >> 6, scolb = off & 63;
    const char* gAp = (const char*)A + (size_t)(m0 + srow) * K * 2 + scolb;
    const char* gBp = (const char*)B + (size_t)(n0 + srow) * K * 2 + scolb;
    char* wA0 = SM + off;
    char* wB0 = SM + 16384 + off;

    GEMM_CORE_D2(16)

    // Et[n][m]: transpose in LDS, write coalesced rows of length 128.
    WG_BARRIER();
    f16* Tt = (f16*)SM;
#pragma unroll
    for (int u = 0; u < 4; ++u)
#pragma unroll
        for (int v = 0; v < 2; ++v) {
            f16x4 p;
#pragma unroll
            for (int r = 0; r < 4; ++r) p[r] = (f16)acc[u][v][r];
            *(f16x4*)&Tt[(wn + v * 16 + col) * 136 + wm + u * 16 + quad * 4] = p;
        }
    WG_BARRIER();
    const int j = tid >> 2, seg = (tid & 3) * 32;
    f16* dst = Et + (size_t)(n0 + j) * 1024 + m0 + seg;
#pragma unroll
    for (int c8 = 0; c8 < 32; c8 += 8)
        *(f16x8*)(dst + c8) = *(const f16x8*)&Tt[j * 136 + seg + c8];
}

// ---------------------------------------------------------------------------
// GEMM3: out[b][c][j] (f32) = n2f[b](f16) @ At[b]^T, with At[j][o] =
// exp(Et[j][o] - Sc[b][o]) computed on the fly during B-staging.
// M=512, N=1024, K=1024. Depth-1 prefetch (carries Sc constants instead).
__global__ __launch_bounds__(512) void gemm3_nt_out(const f16* __restrict__ A,
                                                    const f16* __restrict__ Et,
                                                    const float* __restrict__ Sc,
                                                    float* __restrict__ C) {
    const int K = 1024, NS = 32;
    const int id = blockIdx.x;
    const int xcd = id & 7, loc = id >> 3;
    const int b = xcd * 2 + (loc >> 5);
    const int m0 = ((loc >> 3) & 3) * 128;
    const int n0 = (loc & 7) * 128;
    A += (size_t)b * 512 * K;
    Et += (size_t)b * 1024 * K;
    Sc += (size_t)b * 1024;
    C += (size_t)b * 512 * 1024;
    __shared__ __attribute__((aligned(16))) char SM[32768];
    const int tid = threadIdx.x, lane = tid & 63, wave = tid >> 6;
    const int col = lane & 15, quad = lane >> 4;
    const int wm = (wave & 1) * 64, wn = (wave >> 1) * 32;
    const int off = wave * 1024 + lane * 16;
    const int srow = off >> 6, scolb = off & 63;
    const char* gAp = (const char*)A + (size_t)(m0 + srow) * K * 2 + scolb;
    const char* gBp = (const char*)Et + (size_t)(n0 + srow) * K * 2 + scolb;
    const float* gSp = Sc + (scolb >> 1);  // o-base of this thread's 8 staged elems
    char* wA0 = SM + off;
    char* wB0 = SM + 16384 + off;

    f16x8 ra = *(const f16x8*)gAp, rb = *(const f16x8*)gBp;
    f32x4 c0 = *(const f32x4*)gSp, c1 = *(const f32x4*)(gSp + 4);
    {
        f16x8 rbs;
#pragma unroll
        for (int i = 0; i < 4; ++i) rbs[i] = (f16)__expf((float)rb[i] - c0[i]);
#pragma unroll
        for (int i = 0; i < 4; ++i) rbs[4 + i] = (f16)__expf((float)rb[4 + i] - c1[i]);
        *(f16x8*)wA0 = ra;
        *(f16x8*)wB0 = rbs;
    }
    ra = *(const f16x8*)(gAp + 64);
    rb = *(const f16x8*)(gBp + 64);
    c0 = *(const f32x4*)(gSp + 32);
    c1 = *(const f32x4*)(gSp + 36);
    WG_BARRIER();
    f32x4 acc[4][2] = {};
#pragma unroll
    for (int kb = 0; kb < NS; ++kb) {
        const f16* Ac = (const f16*)(SM + (kb & 1) * 8192);
        const f16* Bc = (const f16*)(SM + 16384 + (kb & 1) * 8192);
        f16x8 fa[4], fb[2];
#pragma unroll
        for (int u = 0; u < 4; ++u)
            fa[u] = *(const f16x8*)&Ac[(wm + u * 16 + col) * 32 + quad * 8];
#pragma unroll
        for (int v = 0; v < 2; ++v)
            fb[v] = *(const f16x8*)&Bc[(wn + v * 16 + col) * 32 + quad * 8];
#pragma unroll
        for (int u = 0; u < 4; ++u)
#pragma unroll
            for (int v = 0; v < 2; ++v)
                acc[u][v] = __builtin_amdgcn_mfma_f32_16x16x32_f16(fa[u], fb[v],
                                                                   acc[u][v], 0, 0, 0);
        if (kb + 1 < NS) {
            char* dA = SM + ((kb + 1) & 1) * 8192 + off;
            char* dB = SM + 16384 + ((kb + 1) & 1) * 8192 + off;
            f16x8 rbs;
#pragma unroll
            for (int i = 0; i < 4; ++i) rbs[i] = (f16)__expf((float)rb[i] - c0[i]);
#pragma unroll
            for (int i = 0; i < 4; ++i) rbs[4 + i] = (f16)__expf((float)rb[4 + i] - c1[i]);
            *(f16x8*)dA = ra;
            *(f16x8*)dB = rbs;
            if (kb + 2 < NS) {
                ra = *(const f16x8*)(gAp + (size_t)(kb + 2) * 64);
                rb = *(const f16x8*)(gBp + (size_t)(kb + 2) * 64);
                c0 = *(const f32x4*)(gSp + (size_t)(kb + 2) * 32);
                c1 = *(const f32x4*)(gSp + (size_t)(kb + 2) * 32 + 4);
            }
            WG_BARRIER();
        }
    }

#pragma unroll
    for (int u = 0; u < 4; ++u)
#pragma unroll
        for (int v = 0; v < 2; ++v)
#pragma unroll
            for (int r = 0; r < 4; ++r)
                C[(size_t)(m0 + wm + u * 16 + quad * 4 + r) * 1024 + n0 + wn + v * 16 + col] =
                    acc[u][v][r];
}

// ---------------------------------------------------------------------------
extern "C" void kernel_launch(void* const* d_in, const int* in_sizes, int n_in,
                              void* d_out, int out_size, void* d_ws, size_t ws_size,
                              hipStream_t stream) {
    const float* n1 = (const float*)d_in[0];
    const float* n2 = (const float*)d_in[1];
    const float* Wc = (const float*)d_in[2];
    float* out = (float*)d_out;
    char* ws = (char*)d_ws;

    f16* n2t = (f16*)(ws);                   // [0,16M)   prep -> gemm2
    f16* Xt  = (f16*)(ws + (16u << 20));     // [16,32M)  gemm1 -> gemm2
    f16* Wf  = (f16*)(ws + (32u << 20));     // [32,34M)  prep -> gemm1 (dead before Et)
    f16* Et  = (f16*)(ws + (32u << 20));     // [32,64M)  gemm2 -> stats -> gemm3
    f16* n1f = (f16*)(ws + (64u << 20));     // [64,80M)  prep -> gemm1 (dead after)
    f16* n2f = (f16*)(ws + (80u << 20));     // [80,96M)  prep -> gemm3
    float* Pm = (float*)(ws + (64u << 20));            // 1 MiB, over dead n1f
    float* Ps = (float*)(ws + (65u << 20));            // 1 MiB
    float* Sc = (float*)(ws + (66u << 20));            // 64 KiB

    prep<<<6656, dim3(256), 0, stream>>>(n1, Wc, n2, n1f, Wf, n2f, n2t);
    gemm1_nt_xt<<<512, dim3(512), 0, stream>>>(n1f, Wf, Xt);
    gemm2_nt_et<<<1024, dim3(512), 0, stream>>>(Xt, n2t, Et);
    stats_partial<<<256, dim3(256), 0, stream>>>(Et, Pm, Ps);
    stats_combine<<<64, dim3(256), 0, stream>>>(Pm, Ps, Sc);
    gemm3_nt_out<<<512, dim3(512), 0, stream>>>(n2f, Et, Sc, out);
}